// Round 18
// baseline (98.743 us; speedup 1.0000x reference)
//
#include <hip/hip_runtime.h>
#include <stdint.h>

#define KCAPS 10
#define OC    16
#define IC    256
#define HWSZ  36
#define PRIM  72
#define PD    8
#define EDIM  16
#define BMAX  2048

typedef short bf16x8 __attribute__((ext_vector_type(8)));
typedef float f32x4  __attribute__((ext_vector_type(4)));

// persistent prepped data (recomputed every launch -> deterministic)
__device__ unsigned short g_whi[KCAPS * OC * IC];
__device__ unsigned short g_wlo[KCAPS * OC * IC];
__device__ float4         g_wtsT4[KCAPS * PD * 4 * PRIM];   // [k][(d*4+e4)][p]
__device__ float          g_caps_fallback[(size_t)BMAX * 160 * HWSZ];

// gemm LDS (76032 B), 2 batch elements (short offsets):
//   elem0: xsh [0,9504) xsl [9504,19008) ; elem1: xsh [19008,28512) xsl [28512,38016)
//   each plane bf16 [36][264]; n-tiles based at hw {0,16,20} -> all reads in-bounds
#define SMEM_G 76032
// route v3 LDS (2 elems): u0[16][724] u1[16][724] | b0[720] b1[720] c0[720] c1[720]
//   | v0[160] v1[160]  = 26368 floats = 105472 B
#define SMEM_R (26368 * 4)

__device__ __forceinline__ void bf_split(float v, unsigned short& hb, unsigned short& lb) {
    __bf16 h = (__bf16)v;
    hb = __builtin_bit_cast(unsigned short, h);
    __bf16 l = (__bf16)(v - (float)h);
    lb = __builtin_bit_cast(unsigned short, l);
}

__device__ __forceinline__ f32x4 mfma16(bf16x8 a, bf16x8 b, f32x4 c) {
    return __builtin_amdgcn_mfma_f32_16x16x32_bf16(a, b, c, 0, 0, 0);
}

__global__ __launch_bounds__(256)
void prep_kernel(const float* __restrict__ w, const float* __restrict__ wts) {
    int i = blockIdx.x * 256 + threadIdx.x;
    if (i < KCAPS * OC * IC) {                 // 40960
        unsigned short hb, lb;
        bf_split(w[i], hb, lb);
        g_whi[i] = hb;
        g_wlo[i] = lb;
    }
    if (i < KCAPS * PD * 4 * PRIM) {           // 23040 float4 tasks
        int p = i % PRIM;
        int r = i / PRIM;
        int e4 = r & 3;
        int d  = (r >> 2) & 7;
        int k  = r >> 5;
        g_wtsT4[i] = *(const float4*)(wts + (size_t)(((k * PRIM + p) * PD + d) * EDIM + e4 * 4));
    }
}

// ---- gemm v3 (R17-proven ~49us): 512 threads, 2 elems, m-split waves, dual-elem acc
__global__ __launch_bounds__(512, 2)
void gemm_caps(const float* __restrict__ x, const float* __restrict__ conv_b,
               float* __restrict__ caps_g) {
    extern __shared__ char smem[];
    uint32_t* xs_u = (uint32_t*)smem;
    const short* xs_s = (const short*)smem;

    const int t   = threadIdx.x;
    const int bb  = blockIdx.x;
    const int w8  = t >> 6;           // 0..7; m-tiles {w8} (+{8+w8} if w8<2)
    const int ln  = t & 63;
    const int row = ln & 15;
    const int g   = ln >> 4;
    const int nm  = (w8 < 2) ? 2 : 1;

    for (int task = t; task < 2304; task += 512) {
        int half = (task >= 1152) ? 1 : 0;
        int tt = task - half * 1152;
        int cp = tt / 9, hq = tt - cp * 9;
        const float4* x4 = (const float4*)(x + (size_t)(2 * bb + half) * (IC * HWSZ));
        float4 va = x4[(2 * cp) * 9 + hq];
        float4 vb = x4[(2 * cp + 1) * 9 + hq];
        uint32_t* xh = xs_u + half * 9504;
        uint32_t* xl = xh + 4752;
        int base = (4 * hq) * 132 + cp;
        unsigned short ha, la, hb, lb;
        bf_split(va.x, ha, la); bf_split(vb.x, hb, lb);
        xh[base]       = (uint32_t)ha | ((uint32_t)hb << 16);
        xl[base]       = (uint32_t)la | ((uint32_t)lb << 16);
        bf_split(va.y, ha, la); bf_split(vb.y, hb, lb);
        xh[base + 132] = (uint32_t)ha | ((uint32_t)hb << 16);
        xl[base + 132] = (uint32_t)la | ((uint32_t)lb << 16);
        bf_split(va.z, ha, la); bf_split(vb.z, hb, lb);
        xh[base + 264] = (uint32_t)ha | ((uint32_t)hb << 16);
        xl[base + 264] = (uint32_t)la | ((uint32_t)lb << 16);
        bf_split(va.w, ha, la); bf_split(vb.w, hb, lb);
        xh[base + 396] = (uint32_t)ha | ((uint32_t)hb << 16);
        xl[base + 396] = (uint32_t)la | ((uint32_t)lb << 16);
    }
    __syncthreads();

    const int hwbase[3] = {0, 16, 20};

    f32x4 acc0[2][3] = {}, acc1[2][3] = {};
    for (int kt = 0; kt < 8; ++kt) {
        bf16x8 bh[2], bl[2];
        #pragma unroll
        for (int mi = 0; mi < 2; ++mi) {
            if (mi < nm) {
                int woff = ((w8 + 8 * mi) * 16 + row) * 256 + kt * 32 + g * 8;
                bh[mi] = *(const bf16x8*)(g_whi + woff);
                bl[mi] = *(const bf16x8*)(g_wlo + woff);
            }
        }
        bf16x8 ah0[3], al0[3], ah1[3], al1[3];
        #pragma unroll
        for (int nt = 0; nt < 3; ++nt) {
            int o2 = (hwbase[nt] + row) * 264 + kt * 32 + g * 8;
            ah0[nt] = *(const bf16x8*)(xs_s + o2);
            al0[nt] = *(const bf16x8*)(xs_s + 9504 + o2);
            ah1[nt] = *(const bf16x8*)(xs_s + 19008 + o2);
            al1[nt] = *(const bf16x8*)(xs_s + 28512 + o2);
        }
        #pragma unroll
        for (int mi = 0; mi < 2; ++mi) {
            if (mi < nm) {
                #pragma unroll
                for (int nt = 0; nt < 3; ++nt) {
                    acc0[mi][nt] = mfma16(ah0[nt], bh[mi], acc0[mi][nt]);
                    acc1[mi][nt] = mfma16(ah1[nt], bh[mi], acc1[mi][nt]);
                    acc0[mi][nt] = mfma16(al0[nt], bh[mi], acc0[mi][nt]);
                    acc1[mi][nt] = mfma16(al1[nt], bh[mi], acc1[mi][nt]);
                    acc0[mi][nt] = mfma16(ah0[nt], bl[mi], acc0[mi][nt]);
                    acc1[mi][nt] = mfma16(ah1[nt], bl[mi], acc1[mi][nt]);
                }
            }
        }
    }

    float* cg0 = caps_g + (size_t)(2 * bb) * (160 * HWSZ);
    float* cg1 = caps_g + (size_t)(2 * bb + 1) * (160 * HWSZ);
    #pragma unroll
    for (int mi = 0; mi < 2; ++mi) {
        if (mi < nm) {
            int m = (w8 + 8 * mi) * 16 + row;
            float bias = conv_b[m];
            #pragma unroll
            for (int nt = 0; nt < 3; ++nt) {
                int hw0 = hwbase[nt] + g * 4;
                if (nt < 2 || g == 3) {
                    float4 o0, o1;
                    o0.x = acc0[mi][nt][0] + bias; o1.x = acc1[mi][nt][0] + bias;
                    o0.y = acc0[mi][nt][1] + bias; o1.y = acc1[mi][nt][1] + bias;
                    o0.z = acc0[mi][nt][2] + bias; o1.z = acc1[mi][nt][2] + bias;
                    o0.w = acc0[mi][nt][3] + bias; o1.w = acc1[mi][nt][3] + bias;
                    *(float4*)(cg0 + m * HWSZ + hw0) = o0;
                    *(float4*)(cg1 + m * HWSZ + hw0) = o1;
                }
            }
        }
    }
}

// ---- route v3: 2 elements per block; wts fragments loaded ONCE, applied to both.
//      Thread halves t<256 / t>=256 run elem0/elem1 routing concurrently.
__global__ __launch_bounds__(512, 2)
void route_kernel(const float* __restrict__ caps_g, float* __restrict__ out) {
    extern __shared__ char smem[];
    float* u0 = (float*)smem;                 // [16][724]
    float* u1 = u0 + 16 * 724;                // [16][724]
    float* b0 = u1 + 16 * 724;                // [720]
    float* b1 = b0 + 720;
    float* c0 = b1 + 720;
    float* c1 = c0 + 720;
    float* v0 = c1 + 720;                     // [160]
    float* v1 = v0 + 160;

    const int t  = threadIdx.x;
    const int bb = blockIdx.x;
    const int half = t >> 8;                  // 0: elem0, 1: elem1 (routing phases)
    const int tl   = t & 255;

    // ---- u-transform for BOTH elems, shared wts fragments (all 512 threads)
    {
        const float4* cgA = (const float4*)(caps_g + (size_t)(2 * bb) * (160 * HWSZ));
        const float4* cgB = (const float4*)(caps_g + (size_t)(2 * bb + 1) * (160 * HWSZ));
        for (int task = t; task < KCAPS * PRIM; task += 512) {
            int k = task / PRIM;
            int p = task - k * PRIM;
            float4 qa0 = cgA[task * 2], qa1 = cgA[task * 2 + 1];
            float4 qb0 = cgB[task * 2], qb1 = cgB[task * 2 + 1];
            float pa[PD] = {qa0.x, qa0.y, qa0.z, qa0.w, qa1.x, qa1.y, qa1.z, qa1.w};
            float pb[PD] = {qb0.x, qb0.y, qb0.z, qb0.w, qb1.x, qb1.y, qb1.z, qb1.w};
            const float4* wb = g_wtsT4 + k * (PD * 4 * PRIM) + p;
            float a0[EDIM] = {}, a1[EDIM] = {};
            #pragma unroll
            for (int d = 0; d < PD; ++d) {
                #pragma unroll
                for (int e4 = 0; e4 < 4; ++e4) {
                    float4 w4 = wb[(d * 4 + e4) * PRIM];    // loaded once, used twice
                    a0[e4 * 4 + 0] = fmaf(pa[d], w4.x, a0[e4 * 4 + 0]);
                    a1[e4 * 4 + 0] = fmaf(pb[d], w4.x, a1[e4 * 4 + 0]);
                    a0[e4 * 4 + 1] = fmaf(pa[d], w4.y, a0[e4 * 4 + 1]);
                    a1[e4 * 4 + 1] = fmaf(pb[d], w4.y, a1[e4 * 4 + 1]);
                    a0[e4 * 4 + 2] = fmaf(pa[d], w4.z, a0[e4 * 4 + 2]);
                    a1[e4 * 4 + 2] = fmaf(pb[d], w4.z, a1[e4 * 4 + 2]);
                    a0[e4 * 4 + 3] = fmaf(pa[d], w4.w, a0[e4 * 4 + 3]);
                    a1[e4 * 4 + 3] = fmaf(pb[d], w4.w, a1[e4 * 4 + 3]);
                }
            }
            #pragma unroll
            for (int e = 0; e < EDIM; ++e) {
                u0[e * 724 + task] = a0[e];
                u1[e * 724 + task] = a1[e];
            }
        }
    }
    __syncthreads();                          // #1 u visible

    float* u_t = half ? u1 : u0;
    float* b_s = half ? b1 : b0;
    float* c_s = half ? c1 : c0;
    float* v_s = half ? v1 : v0;

    // ---- iter 0: c = 0.1 exactly; s + fused squash (16-lane shfl)
    if (tl < KCAPS * EDIM) {
        int k = tl >> 4;
        const float4* ur4 = (const float4*)(u_t + (tl & 15) * 724 + k * PRIM);
        float s = 0.f;
        #pragma unroll
        for (int j = 0; j < 18; ++j) {
            float4 u4 = ur4[j];
            s += (u4.x + u4.y) + (u4.z + u4.w);
        }
        s *= 0.1f;
        float q = s * s;
        q += __shfl_xor(q, 1); q += __shfl_xor(q, 2);
        q += __shfl_xor(q, 4); q += __shfl_xor(q, 8);
        v_s[tl] = s * (q / (1.f + q)) * rsqrtf(q + 1e-8f);
    }
    __syncthreads();                          // #2 v visible

    for (int task = tl; task < KCAPS * PRIM; task += 256) {   // agree 0
        int k = task / PRIM;
        const float* vr = v_s + k * EDIM;
        float dot = 0.f;
        #pragma unroll
        for (int e = 0; e < EDIM; ++e) dot = fmaf(u_t[e * 724 + task], vr[e], dot);
        b_s[task] = dot;
    }
    __syncthreads();                          // #3 b visible

    float vout = 0.f;
    #pragma unroll
    for (int it = 1; it < 3; ++it) {
        if (tl < PRIM) {                      // softmax over k, both elems concurrent
            float bv[KCAPS];
            float m = -1e30f;
            #pragma unroll
            for (int k2 = 0; k2 < KCAPS; ++k2) { bv[k2] = b_s[k2 * PRIM + tl]; m = fmaxf(m, bv[k2]); }
            float sum = 0.f;
            #pragma unroll
            for (int k2 = 0; k2 < KCAPS; ++k2) { bv[k2] = __expf(bv[k2] - m); sum += bv[k2]; }
            float inv = 1.f / sum;
            #pragma unroll
            for (int k2 = 0; k2 < KCAPS; ++k2) c_s[k2 * PRIM + tl] = bv[k2] * inv;
        }
        __syncthreads();                      // c visible

        if (tl < KCAPS * EDIM) {              // s + fused squash
            int k = tl >> 4;
            const float4* ur4 = (const float4*)(u_t + (tl & 15) * 724 + k * PRIM);
            const float4* cr4 = (const float4*)(c_s + k * PRIM);
            float s = 0.f;
            #pragma unroll
            for (int j = 0; j < 18; ++j) {
                float4 u4 = ur4[j];
                float4 c4 = cr4[j];
                s = fmaf(u4.x, c4.x, s);
                s = fmaf(u4.y, c4.y, s);
                s = fmaf(u4.z, c4.z, s);
                s = fmaf(u4.w, c4.w, s);
            }
            float q = s * s;
            q += __shfl_xor(q, 1); q += __shfl_xor(q, 2);
            q += __shfl_xor(q, 4); q += __shfl_xor(q, 8);
            float v = s * (q / (1.f + q)) * rsqrtf(q + 1e-8f);
            if (it < 2) v_s[tl] = v;
            else vout = v;
        }
        __syncthreads();                      // v visible / b reads done

        if (it < 2) {                         // agreement update
            for (int task = tl; task < KCAPS * PRIM; task += 256) {
                int k = task / PRIM;
                const float* vr = v_s + k * EDIM;
                float dot = 0.f;
                #pragma unroll
                for (int e = 0; e < EDIM; ++e) dot = fmaf(u_t[e * 724 + task], vr[e], dot);
                b_s[task] += dot;
            }
            __syncthreads();                  // b updated
        }
    }

    if (tl < KCAPS * EDIM)
        out[(size_t)(2 * bb + half) * (KCAPS * EDIM) + tl] = vout;
}

extern "C" void kernel_launch(void* const* d_in, const int* in_sizes, int n_in,
                              void* d_out, int out_size, void* d_ws, size_t ws_size,
                              hipStream_t stream) {
    const float* x  = (const float*)d_in[0];
    const float* cw = (const float*)d_in[1];
    const float* cb = (const float*)d_in[2];
    const float* wt = (const float*)d_in[3];
    float* out = (float*)d_out;
    const int B = in_sizes[0] / (IC * HWSZ);   // 2048

    size_t capsNeed = (size_t)B * 160 * HWSZ * sizeof(float);   // 47.2 MB
    float* caps_g = nullptr;
    if (d_ws != nullptr && ws_size >= capsNeed) {
        caps_g = (float*)d_ws;
    } else {
        void* sym = nullptr;
        hipGetSymbolAddress(&sym, HIP_SYMBOL(g_caps_fallback));
        caps_g = (float*)sym;
    }

    hipLaunchKernelGGL(prep_kernel, dim3(160), dim3(256), 0, stream, cw, wt);

    hipFuncSetAttribute(reinterpret_cast<const void*>(&gemm_caps),
                        hipFuncAttributeMaxDynamicSharedMemorySize, SMEM_G);
    hipLaunchKernelGGL(gemm_caps, dim3(B / 2), dim3(512), SMEM_G, stream, x, cb, caps_g);

    hipFuncSetAttribute(reinterpret_cast<const void*>(&route_kernel),
                        hipFuncAttributeMaxDynamicSharedMemorySize, SMEM_R);
    hipLaunchKernelGGL(route_kernel, dim3(B / 2), dim3(512), SMEM_R, stream, caps_g, out);
}

// Round 19
// 85.987 us; speedup vs baseline: 1.1484x; 1.1484x over previous
//
#include <hip/hip_runtime.h>
#include <stdint.h>

#define KCAPS 10
#define OC    16
#define IC    256
#define HWSZ  36
#define PRIM  72
#define PD    8
#define EDIM  16
#define BMAX  2048

typedef short bf16x8 __attribute__((ext_vector_type(8)));
typedef float f32x4  __attribute__((ext_vector_type(4)));

// persistent prepped data (recomputed every launch -> deterministic)
__device__ unsigned short g_whi[KCAPS * OC * IC];
__device__ unsigned short g_wlo[KCAPS * OC * IC];
__device__ float4         g_wtsT4[KCAPS * PD * 4 * PRIM];   // [k][(d*4+e4)][p]
__device__ float          g_caps_fallback[(size_t)BMAX * 160 * HWSZ];

// gemm LDS (76032 B), 2 batch elements (short offsets):
//   elem0: xsh [0,9504) xsl [9504,19008) ; elem1: xsh [19008,28512) xsl [28512,38016)
//   each plane bf16 [36][264]; n-tiles based at hw {0,16,20} -> all reads in-bounds
#define SMEM_G 76032
// route v2 LDS: u_t f32[16][724] (46336 B) | b_s[720] | c_s[720] | v_s[160] = 52736 B
#define SMEM_R (13184 * 4)

__device__ __forceinline__ void bf_split(float v, unsigned short& hb, unsigned short& lb) {
    __bf16 h = (__bf16)v;
    hb = __builtin_bit_cast(unsigned short, h);
    __bf16 l = (__bf16)(v - (float)h);
    lb = __builtin_bit_cast(unsigned short, l);
}

__device__ __forceinline__ f32x4 mfma16(bf16x8 a, bf16x8 b, f32x4 c) {
    return __builtin_amdgcn_mfma_f32_16x16x32_bf16(a, b, c, 0, 0, 0);
}

__global__ __launch_bounds__(256)
void prep_kernel(const float* __restrict__ w, const float* __restrict__ wts) {
    int i = blockIdx.x * 256 + threadIdx.x;
    if (i < KCAPS * OC * IC) {                 // 40960
        unsigned short hb, lb;
        bf_split(w[i], hb, lb);
        g_whi[i] = hb;
        g_wlo[i] = lb;
    }
    if (i < KCAPS * PD * 4 * PRIM) {           // 23040 float4 tasks
        int p = i % PRIM;
        int r = i / PRIM;
        int e4 = r & 3;
        int d  = (r >> 2) & 7;
        int k  = r >> 5;
        g_wtsT4[i] = *(const float4*)(wts + (size_t)(((k * PRIM + p) * PD + d) * EDIM + e4 * 4));
    }
}

// ---- gemm v3 (R17-proven ~49us): 512 threads, 2 elems; waves split by M-TILE:
//      wave w8 owns m-tile w8 (+8+w8 for w8<2); dual-elem accumulators give 2
//      independent MFMA chains per (mi,nt); each w fragment loaded by ONE wave.
__global__ __launch_bounds__(512, 2)
void gemm_caps(const float* __restrict__ x, const float* __restrict__ conv_b,
               float* __restrict__ caps_g) {
    extern __shared__ char smem[];
    uint32_t* xs_u = (uint32_t*)smem;
    const short* xs_s = (const short*)smem;

    const int t   = threadIdx.x;
    const int bb  = blockIdx.x;
    const int w8  = t >> 6;           // 0..7; m-tiles {w8} (+{8+w8} if w8<2)
    const int ln  = t & 63;
    const int row = ln & 15;
    const int g   = ln >> 4;
    const int nm  = (w8 < 2) ? 2 : 1;

    // stage BOTH elements transposed -> bf16 hi/lo [36][264], all 512 threads
    for (int task = t; task < 2304; task += 512) {
        int half = (task >= 1152) ? 1 : 0;
        int tt = task - half * 1152;
        int cp = tt / 9, hq = tt - cp * 9;
        const float4* x4 = (const float4*)(x + (size_t)(2 * bb + half) * (IC * HWSZ));
        float4 va = x4[(2 * cp) * 9 + hq];
        float4 vb = x4[(2 * cp + 1) * 9 + hq];
        uint32_t* xh = xs_u + half * 9504;
        uint32_t* xl = xh + 4752;
        int base = (4 * hq) * 132 + cp;
        unsigned short ha, la, hb, lb;
        bf_split(va.x, ha, la); bf_split(vb.x, hb, lb);
        xh[base]       = (uint32_t)ha | ((uint32_t)hb << 16);
        xl[base]       = (uint32_t)la | ((uint32_t)lb << 16);
        bf_split(va.y, ha, la); bf_split(vb.y, hb, lb);
        xh[base + 132] = (uint32_t)ha | ((uint32_t)hb << 16);
        xl[base + 132] = (uint32_t)la | ((uint32_t)lb << 16);
        bf_split(va.z, ha, la); bf_split(vb.z, hb, lb);
        xh[base + 264] = (uint32_t)ha | ((uint32_t)hb << 16);
        xl[base + 264] = (uint32_t)la | ((uint32_t)lb << 16);
        bf_split(va.w, ha, la); bf_split(vb.w, hb, lb);
        xh[base + 396] = (uint32_t)ha | ((uint32_t)hb << 16);
        xl[base + 396] = (uint32_t)la | ((uint32_t)lb << 16);
    }
    __syncthreads();                  // single barrier

    const int hwbase[3] = {0, 16, 20};

    f32x4 acc0[2][3] = {}, acc1[2][3] = {};
    for (int kt = 0; kt < 8; ++kt) {
        bf16x8 bh[2], bl[2];
        #pragma unroll
        for (int mi = 0; mi < 2; ++mi) {
            if (mi < nm) {
                int woff = ((w8 + 8 * mi) * 16 + row) * 256 + kt * 32 + g * 8;
                bh[mi] = *(const bf16x8*)(g_whi + woff);
                bl[mi] = *(const bf16x8*)(g_wlo + woff);
            }
        }
        bf16x8 ah0[3], al0[3], ah1[3], al1[3];
        #pragma unroll
        for (int nt = 0; nt < 3; ++nt) {
            int o2 = (hwbase[nt] + row) * 264 + kt * 32 + g * 8;
            ah0[nt] = *(const bf16x8*)(xs_s + o2);
            al0[nt] = *(const bf16x8*)(xs_s + 9504 + o2);
            ah1[nt] = *(const bf16x8*)(xs_s + 19008 + o2);
            al1[nt] = *(const bf16x8*)(xs_s + 28512 + o2);
        }
        #pragma unroll
        for (int mi = 0; mi < 2; ++mi) {
            if (mi < nm) {
                #pragma unroll
                for (int nt = 0; nt < 3; ++nt) {
                    acc0[mi][nt] = mfma16(ah0[nt], bh[mi], acc0[mi][nt]);
                    acc1[mi][nt] = mfma16(ah1[nt], bh[mi], acc1[mi][nt]);
                    acc0[mi][nt] = mfma16(al0[nt], bh[mi], acc0[mi][nt]);
                    acc1[mi][nt] = mfma16(al1[nt], bh[mi], acc1[mi][nt]);
                    acc0[mi][nt] = mfma16(ah0[nt], bl[mi], acc0[mi][nt]);
                    acc1[mi][nt] = mfma16(ah1[nt], bl[mi], acc1[mi][nt]);
                }
            }
        }
    }

    // C-write (+bias): hw = hwbase[nt]+g*4+r ; tile2 writes only g==3 (hw 32-35)
    float* cg0 = caps_g + (size_t)(2 * bb) * (160 * HWSZ);
    float* cg1 = caps_g + (size_t)(2 * bb + 1) * (160 * HWSZ);
    #pragma unroll
    for (int mi = 0; mi < 2; ++mi) {
        if (mi < nm) {
            int m = (w8 + 8 * mi) * 16 + row;
            float bias = conv_b[m];
            #pragma unroll
            for (int nt = 0; nt < 3; ++nt) {
                int hw0 = hwbase[nt] + g * 4;
                if (nt < 2 || g == 3) {
                    float4 o0, o1;
                    o0.x = acc0[mi][nt][0] + bias; o1.x = acc1[mi][nt][0] + bias;
                    o0.y = acc0[mi][nt][1] + bias; o1.y = acc1[mi][nt][1] + bias;
                    o0.z = acc0[mi][nt][2] + bias; o1.z = acc1[mi][nt][2] + bias;
                    o0.w = acc0[mi][nt][3] + bias; o1.w = acc1[mi][nt][3] + bias;
                    *(float4*)(cg0 + m * HWSZ + hw0) = o0;
                    *(float4*)(cg1 + m * HWSZ + hw0) = o1;
                }
            }
        }
    }
}

// ---- route v2 (R15/R17-proven ~28us): 512 threads, 8 barriers, fused squash,
//      no iter-0 softmax (b=0 -> c=0.1 exactly), final v straight to out.
__global__ __launch_bounds__(512, 2)
void route_kernel(const float* __restrict__ caps_g, float* __restrict__ out) {
    extern __shared__ char smem[];
    float* u_t = (float*)smem;                // [16][724]
    float* b_s = u_t + 16 * 724;              // [720]
    float* c_s = b_s + 720;                   // [720]
    float* v_s = c_s + 720;                   // [160]

    const int t  = threadIdx.x;
    const int bb = blockIdx.x;

    {
        const float4* cg4 = (const float4*)(caps_g + (size_t)bb * (160 * HWSZ));
        for (int task = t; task < KCAPS * PRIM; task += 512) {
            int k = task / PRIM;
            int p = task - k * PRIM;
            float4 c0 = cg4[task * 2];
            float4 c1 = cg4[task * 2 + 1];
            float pv[PD] = {c0.x, c0.y, c0.z, c0.w, c1.x, c1.y, c1.z, c1.w};
            const float4* wb = g_wtsT4 + k * (PD * 4 * PRIM) + p;
            float au[EDIM] = {};
            #pragma unroll
            for (int d = 0; d < PD; ++d) {
                #pragma unroll
                for (int e4 = 0; e4 < 4; ++e4) {
                    float4 w4 = wb[(d * 4 + e4) * PRIM];
                    au[e4 * 4 + 0] = fmaf(pv[d], w4.x, au[e4 * 4 + 0]);
                    au[e4 * 4 + 1] = fmaf(pv[d], w4.y, au[e4 * 4 + 1]);
                    au[e4 * 4 + 2] = fmaf(pv[d], w4.z, au[e4 * 4 + 2]);
                    au[e4 * 4 + 3] = fmaf(pv[d], w4.w, au[e4 * 4 + 3]);
                }
            }
            #pragma unroll
            for (int e = 0; e < EDIM; ++e) u_t[e * 724 + task] = au[e];
        }
    }
    __syncthreads();

    if (t < KCAPS * EDIM) {                   // iter 0: c = 0.1 exactly
        int k = t >> 4;
        const float4* ur4 = (const float4*)(u_t + (t & 15) * 724 + k * PRIM);
        float s = 0.f;
        #pragma unroll
        for (int j = 0; j < 18; ++j) {
            float4 u4 = ur4[j];
            s += (u4.x + u4.y) + (u4.z + u4.w);
        }
        s *= 0.1f;
        float q = s * s;
        q += __shfl_xor(q, 1); q += __shfl_xor(q, 2);
        q += __shfl_xor(q, 4); q += __shfl_xor(q, 8);
        v_s[t] = s * (q / (1.f + q)) * rsqrtf(q + 1e-8f);
    }
    __syncthreads();

    for (int task = t; task < KCAPS * PRIM; task += 512) {   // agree 0
        int k = task / PRIM;
        const float* vr = v_s + k * EDIM;
        float dot = 0.f;
        #pragma unroll
        for (int e = 0; e < EDIM; ++e) dot = fmaf(u_t[e * 724 + task], vr[e], dot);
        b_s[task] = dot;
    }
    __syncthreads();

    float vout = 0.f;
    #pragma unroll
    for (int it = 1; it < 3; ++it) {
        if (t < PRIM) {
            float bv[KCAPS];
            float m = -1e30f;
            #pragma unroll
            for (int k2 = 0; k2 < KCAPS; ++k2) { bv[k2] = b_s[k2 * PRIM + t]; m = fmaxf(m, bv[k2]); }
            float sum = 0.f;
            #pragma unroll
            for (int k2 = 0; k2 < KCAPS; ++k2) { bv[k2] = __expf(bv[k2] - m); sum += bv[k2]; }
            float inv = 1.f / sum;
            #pragma unroll
            for (int k2 = 0; k2 < KCAPS; ++k2) c_s[k2 * PRIM + t] = bv[k2] * inv;
        }
        __syncthreads();

        if (t < KCAPS * EDIM) {
            int k = t >> 4;
            const float4* ur4 = (const float4*)(u_t + (t & 15) * 724 + k * PRIM);
            const float4* cr4 = (const float4*)(c_s + k * PRIM);
            float s = 0.f;
            #pragma unroll
            for (int j = 0; j < 18; ++j) {
                float4 u4 = ur4[j];
                float4 c4 = cr4[j];
                s = fmaf(u4.x, c4.x, s);
                s = fmaf(u4.y, c4.y, s);
                s = fmaf(u4.z, c4.z, s);
                s = fmaf(u4.w, c4.w, s);
            }
            float q = s * s;
            q += __shfl_xor(q, 1); q += __shfl_xor(q, 2);
            q += __shfl_xor(q, 4); q += __shfl_xor(q, 8);
            float v = s * (q / (1.f + q)) * rsqrtf(q + 1e-8f);
            if (it < 2) v_s[t] = v;
            else vout = v;
        }
        __syncthreads();

        if (it < 2) {
            for (int task = t; task < KCAPS * PRIM; task += 512) {
                int k = task / PRIM;
                const float* vr = v_s + k * EDIM;
                float dot = 0.f;
                #pragma unroll
                for (int e = 0; e < EDIM; ++e) dot = fmaf(u_t[e * 724 + task], vr[e], dot);
                b_s[task] += dot;
            }
            __syncthreads();
        }
    }

    if (t < KCAPS * EDIM) out[(size_t)bb * (KCAPS * EDIM) + t] = vout;
}

extern "C" void kernel_launch(void* const* d_in, const int* in_sizes, int n_in,
                              void* d_out, int out_size, void* d_ws, size_t ws_size,
                              hipStream_t stream) {
    const float* x  = (const float*)d_in[0];
    const float* cw = (const float*)d_in[1];
    const float* cb = (const float*)d_in[2];
    const float* wt = (const float*)d_in[3];
    float* out = (float*)d_out;
    const int B = in_sizes[0] / (IC * HWSZ);   // 2048

    size_t capsNeed = (size_t)B * 160 * HWSZ * sizeof(float);   // 47.2 MB
    float* caps_g = nullptr;
    if (d_ws != nullptr && ws_size >= capsNeed) {
        caps_g = (float*)d_ws;
    } else {
        void* sym = nullptr;
        hipGetSymbolAddress(&sym, HIP_SYMBOL(g_caps_fallback));
        caps_g = (float*)sym;
    }

    hipLaunchKernelGGL(prep_kernel, dim3(160), dim3(256), 0, stream, cw, wt);

    hipFuncSetAttribute(reinterpret_cast<const void*>(&gemm_caps),
                        hipFuncAttributeMaxDynamicSharedMemorySize, SMEM_G);
    hipLaunchKernelGGL(gemm_caps, dim3(B / 2), dim3(512), SMEM_G, stream, x, cb, caps_g);

    hipFuncSetAttribute(reinterpret_cast<const void*>(&route_kernel),
                        hipFuncAttributeMaxDynamicSharedMemorySize, SMEM_R);
    hipLaunchKernelGGL(route_kernel, dim3(B), dim3(512), SMEM_R, stream, caps_g, out);
}